// Round 1
// baseline (307.238 us; speedup 1.0000x reference)
//
#include <hip/hip_runtime.h>
#include <hip/hip_bf16.h>
#include <stdint.h>

// Problem constants
#define T_ 7
#define D_ 100
#define KP 704          // padded K (700 -> 704 = 22*32)
#define KSTEPS 22
#define NP 704          // padded N (700 -> 704 = 44*16)
#define NT 44           // n-tiles of 16
#define BM 64           // rows per block
#define OUTC 93
#define OUTP 96
#define NT2 6
#define NPOS 50
#define NDEP 45

typedef __attribute__((ext_vector_type(8))) short bf16x8;
typedef __attribute__((ext_vector_type(4))) float f32x4;

// ws layout (bytes)
#define SZ_WWP (22*44*64*8*2)
#define O_WWP  0
#define O_WOP  (O_WWP + SZ_WWP)
#define SZ_WOP (22*6*64*8*2)
#define O_PTB  (O_WOP + SZ_WOP)
#define SZ_PTB (7*50*704*2)
#define O_DTB  (O_PTB + SZ_PTB)
#define SZ_DTB (7*45*704*2)
#define O_HB   (O_DTB + SZ_DTB)

__device__ __forceinline__ unsigned short f2bf(float f) {
  unsigned u = __float_as_uint(f);
  u += 0x7FFFu + ((u >> 16) & 1u);          // RNE
  return (unsigned short)(u >> 16);
}
__device__ __forceinline__ float bf2f(unsigned short h) {
  return __uint_as_float(((unsigned)h) << 16);
}
__device__ __forceinline__ void addbf8(float* s, const uint4 v) {
  unsigned u0 = v.x, u1 = v.y, u2 = v.z, u3 = v.w;
  s[0] += __uint_as_float(u0 << 16);
  s[1] += __uint_as_float(u0 & 0xFFFF0000u);
  s[2] += __uint_as_float(u1 << 16);
  s[3] += __uint_as_float(u1 & 0xFFFF0000u);
  s[4] += __uint_as_float(u2 << 16);
  s[5] += __uint_as_float(u2 & 0xFFFF0000u);
  s[6] += __uint_as_float(u3 << 16);
  s[7] += __uint_as_float(u3 & 0xFFFF0000u);
}

// ---- prep: pack a f32 [Ksrc x Nsrc] matrix into MFMA B-fragment layout
// out[ks][nt][lane][8] bf16, zero-padded. grid = 22*ntiles blocks x 64 thr.
__global__ void pack_w(const float* __restrict__ W, unsigned short* __restrict__ out,
                       int Ksrc, int Nsrc, int ntiles) {
  int blk = blockIdx.x;
  int ks = blk / ntiles, nt = blk - ks*ntiles;
  int l = threadIdx.x;
  int n = nt*16 + (l & 15);
  int k0 = ks*32 + (l >> 4)*8;
  unsigned short v[8];
#pragma unroll
  for (int j = 0; j < 8; ++j) {
    int k = k0 + j;
    float f = (k < Ksrc && n < Nsrc) ? W[k*Nsrc + n] : 0.f;
    v[j] = f2bf(f);
  }
  ((uint4*)out)[blk*64 + l] = *(const uint4*)v;
}

// ---- prep: PT[t][p][h] = sum_d tbl[p][d] * W[t*100+d][h], bf16, h padded to 704
__global__ void pack_tbl(const float* __restrict__ tbl, const float* __restrict__ W,
                         unsigned short* __restrict__ out, int P, int total) {
  int id = blockIdx.x*256 + threadIdx.x;
  if (id >= total) return;
  int hp = id % 704;
  int tp = id / 704;
  int p = tp % P, t = tp / P;
  float acc = 0.f;
  if (hp < 700) {
    const float* tr = tbl + p*100;
    const float* wc = W + t*100*700 + hp;
#pragma unroll 4
    for (int d = 0; d < 100; ++d) acc += tr[d] * wc[d*700];
  }
  out[id] = f2bf(acc);
}

__global__ void bias_sum(const float* __restrict__ a, const float* __restrict__ b,
                         const float* __restrict__ c, float* __restrict__ o) {
  int i = blockIdx.x*256 + threadIdx.x;
  if (i < 704) o[i] = (i < 700) ? (a[i] + b[i] + c[i]) : 0.f;
}

// ---- main fused kernel: word-GEMM (MFMA) + PT/DT gather-sum + cube + out-GEMM + softmax
struct SMem {
  union {
    struct { unsigned short A[2][4*64*8]; unsigned short Bb[2][44*64*8]; } mm; // 98304 B
    struct { unsigned short h3[64*712]; float logits[64*96]; } ep;             // 115712 B
  } u;
  int widx[64][8];
  int pidxs[64][8];
  int didxs[64][8];
  float bo_l[96];
};

__launch_bounds__(512, 2)
__global__ void dp_main(const int* __restrict__ word_idx,
                        const int* __restrict__ pos_idx,
                        const int* __restrict__ dep_idx,
                        const float* __restrict__ word_table,
                        const unsigned short* __restrict__ WwP,
                        const unsigned short* __restrict__ WoP,
                        const unsigned short* __restrict__ PTb,
                        const unsigned short* __restrict__ DTb,
                        const float* __restrict__ hbias,
                        const float* __restrict__ bo,
                        float* __restrict__ out) {
  __shared__ SMem sm;
  const int tid = threadIdx.x;
  const int lane = tid & 63;
  const int w = tid >> 6;
  const int blockRow = blockIdx.x * BM;

  // stage indices for this block's 64 rows
  if (tid < 448) {
    int r = tid / 7, t = tid - r*7;
    int g = (blockRow + r)*7 + t;
    sm.widx[r][t]  = word_idx[g];
    sm.pidxs[r][t] = pos_idx[g];
    sm.didxs[r][t] = dep_idx[g];
  }
  if (tid < 96) sm.bo_l[tid] = (tid < OUTC) ? bo[tid] : 0.f;

  f32x4 acc0[11], acc1[11];
#pragma unroll
  for (int j = 0; j < 11; ++j) { acc0[j] = (f32x4){0,0,0,0}; acc1[j] = (f32x4){0,0,0,0}; }

  __syncthreads();

  // --- staging helpers ---
  auto issueB = [&](int ks, int buf) {
    const unsigned short* src = WwP + (size_t)ks*(44*64*8);
    unsigned short* dst = sm.u.mm.Bb[buf];
#pragma unroll
    for (int it = 0; it < 6; ++it) {
      int slot = it*512 + tid;
      if (slot < 44*64) {
        __builtin_amdgcn_global_load_lds(
            (const __attribute__((address_space(1))) unsigned int*)(src + slot*8),
            (__attribute__((address_space(3))) unsigned int*)(dst + slot*8),
            16, 0, 0);
      }
    }
  };
  // gather A fragment source (tid<256): two float4 from word_table (or zeros)
  auto gatherA = [&](int ks, float4& fa, float4& fb) {
    int mt = tid >> 6;               // 0..3
    int l = tid & 63;
    int row = mt*16 + (l & 15);
    int k0 = ks*32 + (l >> 4)*8;
    int t0 = k0 / 100, d0 = k0 - t0*100;     // k0 <= 696 -> t0 <= 6
    fa = make_float4(0.f,0.f,0.f,0.f);
    fb = make_float4(0.f,0.f,0.f,0.f);
    {
      int wi = sm.widx[row][t0];
      if (wi >= 0) fa = *(const float4*)(word_table + (size_t)wi*100 + d0);
    }
    int k4 = k0 + 4; int t1 = k4 / 100, d1 = k4 - t1*100;
    if (t1 < 7) {
      int wi = sm.widx[row][t1];
      if (wi >= 0) fb = *(const float4*)(word_table + (size_t)wi*100 + d1);
    }
  };
  auto writeA = [&](int buf, float4 fa, float4 fb) {
    unsigned short v[8];
    v[0]=f2bf(fa.x); v[1]=f2bf(fa.y); v[2]=f2bf(fa.z); v[3]=f2bf(fa.w);
    v[4]=f2bf(fb.x); v[5]=f2bf(fb.y); v[6]=f2bf(fb.z); v[7]=f2bf(fb.w);
    ((uint4*)sm.u.mm.A[buf])[tid] = *(const uint4*)v;
  };
  const int mtb = (w >> 2) * 2;     // waves 0-3 -> mtiles 0,1 ; waves 4-7 -> 2,3
  const int ntb = (w & 3) * 11;     // 11 n-tiles per wave
  auto compute = [&](int buf) {
    const bf16x8* Af = (const bf16x8*)sm.u.mm.A[buf];
    const bf16x8* Bf = (const bf16x8*)sm.u.mm.Bb[buf];
    bf16x8 a0 = Af[(mtb + 0)*64 + lane];
    bf16x8 a1 = Af[(mtb + 1)*64 + lane];
#pragma unroll
    for (int j = 0; j < 11; ++j) {
      bf16x8 b = Bf[(ntb + j)*64 + lane];
      acc0[j] = __builtin_amdgcn_mfma_f32_16x16x32_bf16(a0, b, acc0[j], 0, 0, 0);
      acc1[j] = __builtin_amdgcn_mfma_f32_16x16x32_bf16(a1, b, acc1[j], 0, 0, 0);
    }
  };

  // --- prologue: stage k-step 0 ---
  issueB(0, 0);
  if (tid < 256) {
    float4 fa, fb;
    gatherA(0, fa, fb);
    writeA(0, fa, fb);
  }
  __syncthreads();

  // --- main K loop (T14: issue loads early, ds_write late) ---
  int buf = 0;
  for (int ks = 0; ks < KSTEPS; ++ks) {
    float4 na, nb;
    const bool pre = (ks + 1 < KSTEPS);
    if (pre) {
      issueB(ks + 1, buf ^ 1);
      if (tid < 256) gatherA(ks + 1, na, nb);
    }
    compute(buf);
    if (pre && tid < 256) writeA(buf ^ 1, na, nb);
    __syncthreads();
    buf ^= 1;
  }

  // --- epilogue 1: S = hbias + sum_t PT[t,pos] + DT[t,dep], bf16 into h3 LDS ---
  {
    unsigned short* h3 = sm.u.ep.h3;
#pragma unroll 1
    for (int it = 0; it < 11; ++it) {
      int v = it*512 + tid;              // 0..5631 (64 rows * 88 col-chunks)
      int row = v / 88;
      int c8 = v - row*88;
      int cb = c8*8;
      float s0[8];
      float4 hb0 = *(const float4*)(hbias + cb);
      float4 hb1 = *(const float4*)(hbias + cb + 4);
      s0[0]=hb0.x; s0[1]=hb0.y; s0[2]=hb0.z; s0[3]=hb0.w;
      s0[4]=hb1.x; s0[5]=hb1.y; s0[6]=hb1.z; s0[7]=hb1.w;
#pragma unroll
      for (int t = 0; t < 7; ++t) {
        int p = sm.pidxs[row][t];
        addbf8(s0, *(const uint4*)(PTb + ((size_t)(t*NPOS + p))*704 + cb));
        int dd = sm.didxs[row][t];
        addbf8(s0, *(const uint4*)(DTb + ((size_t)(t*NDEP + dd))*704 + cb));
      }
      unsigned short o[8];
#pragma unroll
      for (int j = 0; j < 8; ++j) o[j] = f2bf(s0[j]);
      *(uint4*)(h3 + row*712 + cb) = *(const uint4*)o;
    }
  }
  __syncthreads();

  // --- epilogue 2: h3 = (acc_word + S)^3 (bf16, in place) ---
  {
    unsigned short* h3 = sm.u.ep.h3;
    const int lr = (lane >> 4)*4, lc = lane & 15;
#pragma unroll
    for (int j = 0; j < 11; ++j) {
      int col = (ntb + j)*16 + lc;
      {
        int rb = (mtb + 0)*16 + lr;
#pragma unroll
        for (int r = 0; r < 4; ++r) {
          int off = (rb + r)*712 + col;
          float h = acc0[j][r] + bf2f(h3[off]);
          h3[off] = f2bf(h*h*h);
        }
      }
      {
        int rb = (mtb + 1)*16 + lr;
#pragma unroll
        for (int r = 0; r < 4; ++r) {
          int off = (rb + r)*712 + col;
          float h = acc1[j][r] + bf2f(h3[off]);
          h3[off] = f2bf(h*h*h);
        }
      }
    }
  }
  __syncthreads();

  // --- epilogue 3: logits = h3 @ Wo (MFMA, N=96, K=704) ---
  {
    const unsigned short* h3 = sm.u.ep.h3;
    int mt = w >> 1;
    int nb2 = (w & 1)*3;
    f32x4 c2[3];
#pragma unroll
    for (int jn = 0; jn < 3; ++jn) c2[jn] = (f32x4){0,0,0,0};
    const bf16x8* WoF = (const bf16x8*)WoP;
    bf16x8 bfr[3];
#pragma unroll
    for (int jn = 0; jn < 3; ++jn) bfr[jn] = WoF[(size_t)(nb2 + jn)*64 + lane];
    const int arow = mt*16 + (lane & 15);
    const int koff = (lane >> 4)*8;
    for (int ks = 0; ks < KSTEPS; ++ks) {
      bf16x8 a = *(const bf16x8*)(h3 + arow*712 + ks*32 + koff);
      bf16x8 bn[3];
      if (ks < KSTEPS-1) {
#pragma unroll
        for (int jn = 0; jn < 3; ++jn) bn[jn] = WoF[((size_t)(ks+1)*6 + nb2 + jn)*64 + lane];
      }
#pragma unroll
      for (int jn = 0; jn < 3; ++jn)
        c2[jn] = __builtin_amdgcn_mfma_f32_16x16x32_bf16(a, bfr[jn], c2[jn], 0, 0, 0);
      if (ks < KSTEPS-1) {
#pragma unroll
        for (int jn = 0; jn < 3; ++jn) bfr[jn] = bn[jn];
      }
    }
    float* lg = sm.u.ep.logits;
    const int lr = (lane >> 4)*4, lc = lane & 15;
#pragma unroll
    for (int jn = 0; jn < 3; ++jn)
#pragma unroll
      for (int r = 0; r < 4; ++r)
        lg[(mt*16 + lr + r)*96 + (nb2 + jn)*16 + lc] = c2[jn][r];
  }
  __syncthreads();

  // --- epilogue 4: softmax over 93 classes, 8 threads per row ---
  {
    const float* lg = sm.u.ep.logits;
    int row = tid >> 3, s = tid & 7;
    const float4* lp = (const float4*)(lg + row*96 + s*12);
    float4 xa = lp[0], xb = lp[1], xc = lp[2];
    float x[12] = {xa.x,xa.y,xa.z,xa.w, xb.x,xb.y,xb.z,xb.w, xc.x,xc.y,xc.z,xc.w};
    int cb = s*12;
    float mx = -1e30f;
#pragma unroll
    for (int i = 0; i < 12; ++i) {
      int c = cb + i;
      x[i] += sm.bo_l[c];
      mx = fmaxf(mx, (c < OUTC) ? x[i] : -1e30f);
    }
    mx = fmaxf(mx, __shfl_xor(mx, 1, 8));
    mx = fmaxf(mx, __shfl_xor(mx, 2, 8));
    mx = fmaxf(mx, __shfl_xor(mx, 4, 8));
    float e[12]; float sum = 0.f;
#pragma unroll
    for (int i = 0; i < 12; ++i) {
      int c = cb + i;
      e[i] = (c < OUTC) ? __expf(x[i] - mx) : 0.f;
      sum += e[i];
    }
    sum += __shfl_xor(sum, 1, 8);
    sum += __shfl_xor(sum, 2, 8);
    sum += __shfl_xor(sum, 4, 8);
    float inv = 1.0f / sum;
    float* op = out + (size_t)(blockRow + row)*OUTC;
#pragma unroll
    for (int i = 0; i < 12; ++i) {
      int c = cb + i;
      if (c < OUTC) op[c] = e[i]*inv;
    }
  }
}

extern "C" void kernel_launch(void* const* d_in, const int* in_sizes, int n_in,
                              void* d_out, int out_size, void* d_ws, size_t ws_size,
                              hipStream_t stream) {
  const int*   word_idx   = (const int*)d_in[0];
  const int*   pos_idx    = (const int*)d_in[1];
  const int*   dep_idx    = (const int*)d_in[2];
  const float* word_table = (const float*)d_in[3];
  const float* pos_table  = (const float*)d_in[4];
  const float* dep_table  = (const float*)d_in[5];
  const float* Ww = (const float*)d_in[6];
  const float* bw = (const float*)d_in[7];
  const float* Wp = (const float*)d_in[8];
  const float* bp = (const float*)d_in[9];
  const float* Wd = (const float*)d_in[10];
  const float* bd = (const float*)d_in[11];
  const float* Wo = (const float*)d_in[12];
  const float* bo = (const float*)d_in[13];
  float* out = (float*)d_out;

  char* ws = (char*)d_ws;
  unsigned short* WwP   = (unsigned short*)(ws + O_WWP);
  unsigned short* WoP   = (unsigned short*)(ws + O_WOP);
  unsigned short* PTb   = (unsigned short*)(ws + O_PTB);
  unsigned short* DTb   = (unsigned short*)(ws + O_DTB);
  float*          hbias = (float*)(ws + O_HB);

  pack_w<<<22*44, 64, 0, stream>>>(Ww, WwP, 700, 700, 44);
  pack_w<<<22*6,  64, 0, stream>>>(Wo, WoP, 700, OUTC, 6);
  pack_tbl<<<(7*50*704 + 255)/256, 256, 0, stream>>>(pos_table, Wp, PTb, 50, 7*50*704);
  pack_tbl<<<(7*45*704 + 255)/256, 256, 0, stream>>>(dep_table, Wd, DTb, 45, 7*45*704);
  bias_sum<<<3, 256, 0, stream>>>(bw, bp, bd, hbias);
  dp_main<<<65536/BM, 512, 0, stream>>>(word_idx, pos_idx, dep_idx, word_table,
                                        WwP, WoP, PTb, DTb, hbias, bo, out);
}